// Round 17
// baseline (766.019 us; speedup 1.0000x reference)
//
#include <hip/hip_runtime.h>
#include <hip/hip_bf16.h>
#include <math.h>

#define Bq 128
#define Nn 6
#define Dc 256
#define PP 25
#define SAMP 768
#define CHW 6400
#define SAMPLE_F 38400
#define QKD 800
#define KTOT 2304           // 9 taps * 256 ci
#define CROW 264            // LDS row: 256 ci + 8 pad shorts (528 B)
#define CSAMP (26*CROW)     // 25 pixels + 1 zero row
#define TS 2                // samples per conv block

typedef short bf16x8 __attribute__((ext_vector_type(8)));
typedef float f32x4 __attribute__((ext_vector_type(4)));

__device__ __forceinline__ short f2b(float f) {
  unsigned u = __float_as_uint(f);
  unsigned r = (u + 0x7FFFu + ((u >> 16) & 1u)) >> 16;
  return (short)r;
}
__device__ __forceinline__ float b2f(short s) {
  return __uint_as_float(((unsigned)(unsigned short)s) << 16);
}
__device__ __forceinline__ int pack2(short a, short b) {
  return (int)(((unsigned)(unsigned short)a) | (((unsigned)(unsigned short)b) << 16));
}
// 8 bf16 (int4) -> 8 f32
__device__ __forceinline__ void b8f(const int4 v, float* f) {
  unsigned x0 = (unsigned)v.x, x1 = (unsigned)v.y;
  unsigned x2 = (unsigned)v.z, x3 = (unsigned)v.w;
  f[0] = __uint_as_float(x0 << 16); f[1] = __uint_as_float(x0 & 0xffff0000u);
  f[2] = __uint_as_float(x1 << 16); f[3] = __uint_as_float(x1 & 0xffff0000u);
  f[4] = __uint_as_float(x2 << 16); f[5] = __uint_as_float(x2 & 0xffff0000u);
  f[6] = __uint_as_float(x3 << 16); f[7] = __uint_as_float(x3 & 0xffff0000u);
}

// ---------------------------------------------------------------------------
// weight repack (5 sets) into MFMA-fragment-contiguous layout:
// Wpk[z][ct][tap][kb][lane*8+i]
// ---------------------------------------------------------------------------
__global__ __launch_bounds__(256) void k_repack5(const float* __restrict__ self_w,
    const float* __restrict__ rel_w, const float* __restrict__ aff_w,
    const float* __restrict__ aggt_w, short* __restrict__ WbAll) {
  int z = blockIdx.y;
  int idx = blockIdx.x * 256 + threadIdx.x;   // 0..589823
  const float* W; int stride, cioff;
  if (z == 0)      { W = self_w; stride = 2304; cioff = 0; }
  else if (z == 1) { W = rel_w;  stride = 4608; cioff = 0; }
  else if (z == 2) { W = rel_w;  stride = 4608; cioff = 256; }
  else if (z == 3) { W = aff_w;  stride = 2304; cioff = 0; }
  else             { W = aggt_w; stride = 2304; cioff = 0; }
  int chunk = idx >> 9;            // ct*72 + tap*8 + kb
  int within = idx & 511;
  int l = within >> 3, i = within & 7;
  int ct = chunk / 72, rem = chunk - ct * 72;
  int tap = rem >> 3, kb = rem & 7;
  int co = ct * 16 + (l & 15);
  int ci = kb * 32 + (l >> 4) * 8 + i;
  WbAll[(size_t)z * (Dc * KTOT) + idx] =
      f2b(W[(size_t)co * stride + (size_t)(cioff + ci) * 9 + tap]);
}

// ---------------------------------------------------------------------------
// big f32 -> bf16 convert, 8 elems/thread (n = 40,960,000)
// ---------------------------------------------------------------------------
__global__ __launch_bounds__(256) void k_cvtw(const float* __restrict__ in,
    short* __restrict__ out) {
  size_t i = ((size_t)blockIdx.x * 256 + threadIdx.x) * 8;
  float4 a = *(const float4*)(in + i);
  float4 b = *(const float4*)(in + i + 4);
  int4 o;
  o.x = pack2(f2b(a.x), f2b(a.y));
  o.y = pack2(f2b(a.z), f2b(a.w));
  o.z = pack2(f2b(b.x), f2b(b.y));
  o.w = pack2(f2b(b.z), f2b(b.w));
  *(int4*)(out + i) = o;
}

// ---------------------------------------------------------------------------
// fused: 1x1 conv s2d[row, c*25+pq] + transposed bf16 XT[row][pq][ci]
// ---------------------------------------------------------------------------
__global__ __launch_bounds__(256) void k_s2dx(const float* __restrict__ x,
    const float* __restrict__ attn_w, const float* __restrict__ attn_b,
    float* __restrict__ s2d, short* __restrict__ XT) {
  __shared__ float xs[CHW];
  __shared__ short lt[25 * CROW];
  int row = blockIdx.x;
  int t = threadIdx.x;
  const float* xr = x + (size_t)row * CHW;
  for (int i = t; i < CHW; i += 256) xs[i] = xr[i];
  __syncthreads();
  for (int e = t; e < CHW; e += 256) {
    int ci = e / 25, pq = e - ci * 25;
    lt[pq * CROW + ci] = f2b(xs[e]);
  }
  for (int o = t; o < QKD; o += 256) {
    int c = o / PP, pq = o % PP;
    float acc = attn_b[c];
    const float* wr = attn_w + c * Dc;
    for (int ci = 0; ci < Dc; ++ci) acc += wr[ci] * xs[ci * PP + pq];
    s2d[(size_t)row * QKD + o] = acc;
  }
  __syncthreads();
  short* ob = XT + (size_t)row * CHW;
  for (int c = t; c < 800; c += 256) {
    int pix = c >> 5, ch = c & 31;
    *(int4*)(ob + pix * 256 + ch * 8) = *(const int4*)(lt + pix * CROW + ch * 8);
  }
}

// ---------------------------------------------------------------------------
// 3-way bf16 split + fragment-contiguous repack
// ---------------------------------------------------------------------------
__global__ __launch_bounds__(512) void k_split3(const float* __restrict__ in,
    short* __restrict__ pl, int R, int T) {
  int tile = blockIdx.x / 25, kb = blockIdx.x % 25;
  int t = threadIdx.x;
  int l = t >> 3, i = t & 7;
  int row = tile * 16 + (l & 15);
  int k = kb * 32 + (l >> 4) * 8 + i;
  float x = (row < R) ? in[(size_t)row * QKD + k] : 0.f;
  short h = f2b(x);
  float r1 = x - b2f(h);
  short m = f2b(r1);
  float r2 = r1 - b2f(m);
  short lo = f2b(r2);
  size_t PT = (size_t)T * 25 * 512;
  size_t off = ((size_t)tile * 25 + kb) * 512 + t;
  pl[off] = h;
  pl[PT + off] = m;
  pl[2 * PT + off] = lo;
}

// ---------------------------------------------------------------------------
// q GEMM via MFMA, bf16x3 operands (6 products -> ~f32 precision).
// ---------------------------------------------------------------------------
__global__ __launch_bounds__(512) void k_qgemm(const short* __restrict__ Ap,
    const short* __restrict__ Bp, float* __restrict__ qp) {
  int t = threadIdx.x;
  int nT = blockIdx.x, mT = blockIdx.y, kz = blockIdx.z;
  int lane = t & 63, wv = t >> 6;
  int wm = wv >> 2, wn = wv & 3;
  int col = lane & 15, kg = lane >> 4;
  const size_t PTA = (size_t)48 * 25 * 512;
  const size_t PTB = (size_t)56 * 25 * 512;

  f32x4 acc[4][2] = {};
#pragma unroll
  for (int kk = 0; kk < 5; ++kk) {
    int kb = kz * 5 + kk;
    bf16x8 bh[2], bm[2], bl[2];
#pragma unroll
    for (int nt = 0; nt < 2; ++nt) {
      size_t off = ((size_t)(nT * 8 + wn * 2 + nt) * 25 + kb) * 512 + lane * 8;
      bh[nt] = *(const bf16x8*)(Bp + off);
      bm[nt] = *(const bf16x8*)(Bp + PTB + off);
      bl[nt] = *(const bf16x8*)(Bp + 2 * PTB + off);
    }
#pragma unroll
    for (int mt = 0; mt < 4; ++mt) {
      size_t off = ((size_t)(mT * 8 + wm * 4 + mt) * 25 + kb) * 512 + lane * 8;
      bf16x8 ah = *(const bf16x8*)(Ap + off);
      bf16x8 am = *(const bf16x8*)(Ap + PTA + off);
      bf16x8 al = *(const bf16x8*)(Ap + 2 * PTA + off);
#pragma unroll
      for (int nt = 0; nt < 2; ++nt) {
        acc[mt][nt] = __builtin_amdgcn_mfma_f32_16x16x32_bf16(ah, bh[nt], acc[mt][nt], 0, 0, 0);
        acc[mt][nt] = __builtin_amdgcn_mfma_f32_16x16x32_bf16(ah, bm[nt], acc[mt][nt], 0, 0, 0);
        acc[mt][nt] = __builtin_amdgcn_mfma_f32_16x16x32_bf16(am, bh[nt], acc[mt][nt], 0, 0, 0);
        acc[mt][nt] = __builtin_amdgcn_mfma_f32_16x16x32_bf16(ah, bl[nt], acc[mt][nt], 0, 0, 0);
        acc[mt][nt] = __builtin_amdgcn_mfma_f32_16x16x32_bf16(al, bh[nt], acc[mt][nt], 0, 0, 0);
        acc[mt][nt] = __builtin_amdgcn_mfma_f32_16x16x32_bf16(am, bm[nt], acc[mt][nt], 0, 0, 0);
      }
    }
  }
  float* Q = qp + (size_t)kz * SAMP * QKD;
#pragma unroll
  for (int mt = 0; mt < 4; ++mt) {
    int gr = mT * 128 + wm * 64 + mt * 16 + kg * 4;
#pragma unroll
    for (int nt = 0; nt < 2; ++nt) {
      int gc = nT * 128 + wn * 32 + nt * 16 + col;
      if (gc >= QKD) continue;
#pragma unroll
      for (int r = 0; r < 4; ++r)
        Q[(size_t)(gr + r) * QKD + gc] = acc[mt][nt][r];
    }
  }
}

// ---------------------------------------------------------------------------
// attn: sum 5 q-partials (LDS), 36 dots, masked softmax -> sm[b][36]
// ---------------------------------------------------------------------------
__global__ __launch_bounds__(256) void k_attn5(const float* __restrict__ qp,
    const float* __restrict__ valid, float* __restrict__ sm) {
  __shared__ float q[6 * QKD];
  __shared__ float at[36];
  int b = blockIdx.x, t = threadIdx.x;
  size_t base = (size_t)b * 6 * QKD;
  const size_t PS = (size_t)SAMP * QKD;
  for (int i = t; i < 6 * QKD; i += 256) {
    q[i] = qp[base + i] + qp[PS + base + i] + qp[2 * PS + base + i]
         + qp[3 * PS + base + i] + qp[4 * PS + base + i];
  }
  __syncthreads();
  if (t < 36) {
    int n = t / 6, m = t % 6;
    const float4* qn = (const float4*)&q[n * QKD];
    const float4* qm = (const float4*)&q[m * QKD];
    float acc = 0.f;
    for (int d = 0; d < QKD / 4; ++d) {
      float4 a = qn[d], c = qm[d];
      acc += a.x * c.x + a.y * c.y + a.z * c.z + a.w * c.w;
    }
    at[t] = acc * 0.035355339059327376f * valid[b * 6 + m];
  }
  __syncthreads();
  if (t < 6) {
    float v[6]; float mx = -1e30f;
#pragma unroll
    for (int m = 0; m < 6; ++m) {
      float a = at[t * 6 + m];
      v[m] = (a > 0.f) ? a : -1e30f;
      mx = fmaxf(mx, v[m]);
    }
    float e[6]; float se = 0.f;
#pragma unroll
    for (int m = 0; m < 6; ++m) { e[m] = expf(v[m] - mx); se += e[m]; }
    float sc = 6.f / se;
#pragma unroll
    for (int m = 0; m < 6; ++m) sm[(size_t)b * 36 + t * 6 + m] = e[m] * sc;
  }
}

// ---------------------------------------------------------------------------
// MFMA 3x3 conv from pre-transposed bf16 input XT[s][pix][ci].
// Block: 2 samples x 256 co. Wave = (sample wv&1, co-half wv>>1):
// mt=8 co-tiles x nt=2 pixel-tiles -> each LDS read feeds 8 MFMAs.
// Depth-2 register prefetch of weights. __launch_bounds__(256,2): allocator
// budget 256 VGPR (needs ~170 live: acc 64 + wA/wB 64 + addressing) -> no
// spill (round-16 default bounds spilled at 96 VGPR, 2x regression).
// ---------------------------------------------------------------------------
__global__ __launch_bounds__(256, 2) void k_convT(const short* __restrict__ XT,
    const short* __restrict__ WbBase, float* __restrict__ YBase,
    const float* __restrict__ bias, short* __restrict__ Ybf,
    size_t wStride, size_t yStride) {
  __shared__ __align__(16) short xpt[TS * CSAMP];   // 27,456 B
  int t = threadIdx.x;
  int s0 = blockIdx.x * TS;
  int z = blockIdx.y;
  const short* Wb = WbBase + (size_t)z * wStride;
  float* Y = YBase ? (YBase + (size_t)z * yStride) : nullptr;
  int hasBR = (z == 0);

  if (t < TS * 33) {
    int smp = t / 33, i4 = t - smp * 33;
    *(int4*)(xpt + smp * CSAMP + 25 * CROW + i4 * 8) = int4{0, 0, 0, 0};
  }
  for (int c = t; c < TS * 800; c += 256) {
    int smp = c / 800, rem = c - smp * 800;
    int pix = rem >> 5, ch = rem & 31;
    *(int4*)(xpt + smp * CSAMP + pix * CROW + ch * 8) =
        *(const int4*)(XT + ((size_t)(s0 + smp) * 25 + pix) * 256 + ch * 8);
  }
  __syncthreads();

  int lane = t & 63, wv = t >> 6;
  int smp = wv & 1, half = wv >> 1;
  int col = lane & 15, kg = lane >> 4;
  int smpbase = smp * CSAMP;
  const short* wbase = Wb + ((size_t)half * 8 * 72) * 512 + lane * 8;
  int o0 = col, o1 = col + 16;
  int orow0 = o0 / 5, ocol0 = o0 - orow0 * 5;
  int orow1 = o1 / 5, ocol1 = o1 - orow1 * 5;

  bf16x8 wA[8], wB[8];
#pragma unroll
  for (int mt = 0; mt < 8; ++mt)
    wA[mt] = *(const bf16x8*)(wbase + (size_t)(mt * 72) * 512);
#pragma unroll
  for (int mt = 0; mt < 8; ++mt)
    wB[mt] = *(const bf16x8*)(wbase + (size_t)(mt * 72 + 1) * 512);

  f32x4 acc[8][2] = {};
  for (int tap = 0; tap < 9; ++tap) {
    int dh = tap / 3 - 1, dw = tap % 3 - 1;
    int pb0, pb1;
    {
      int irow = orow0 + dh, icol = ocol0 + dw;
      bool good = ((unsigned)irow < 5u) && ((unsigned)icol < 5u);
      pb0 = smpbase + (good ? irow * 5 + icol : 25) * CROW + kg * 8;
    }
    {
      int irow = orow1 + dh, icol = ocol1 + dw;
      bool good = ((unsigned)irow < 5u) && ((unsigned)icol < 5u) && (o1 < 25);
      pb1 = smpbase + (good ? irow * 5 + icol : 25) * CROW + kg * 8;
    }
#pragma unroll
    for (int kb2 = 0; kb2 < 4; ++kb2) {
      int it = tap * 8 + kb2 * 2;
      {   // even step: consume wA (chunk it)
        int kb = kb2 * 2;
        bf16x8 b0 = *(const bf16x8*)(xpt + pb0 + kb * 32);
        bf16x8 b1 = *(const bf16x8*)(xpt + pb1 + kb * 32);
#pragma unroll
        for (int mt = 0; mt < 8; ++mt) {
          acc[mt][0] = __builtin_amdgcn_mfma_f32_16x16x32_bf16(wA[mt], b0, acc[mt][0], 0, 0, 0);
          acc[mt][1] = __builtin_amdgcn_mfma_f32_16x16x32_bf16(wA[mt], b1, acc[mt][1], 0, 0, 0);
        }
      }
      if (it + 2 < 72) {
#pragma unroll
        for (int mt = 0; mt < 8; ++mt)
          wA[mt] = *(const bf16x8*)(wbase + (size_t)(mt * 72 + it + 2) * 512);
      }
      {   // odd step: consume wB (chunk it+1)
        int kb = kb2 * 2 + 1;
        bf16x8 b0 = *(const bf16x8*)(xpt + pb0 + kb * 32);
        bf16x8 b1 = *(const bf16x8*)(xpt + pb1 + kb * 32);
#pragma unroll
        for (int mt = 0; mt < 8; ++mt) {
          acc[mt][0] = __builtin_amdgcn_mfma_f32_16x16x32_bf16(wB[mt], b0, acc[mt][0], 0, 0, 0);
          acc[mt][1] = __builtin_amdgcn_mfma_f32_16x16x32_bf16(wB[mt], b1, acc[mt][1], 0, 0, 0);
        }
      }
      if (it + 3 < 72) {
#pragma unroll
        for (int mt = 0; mt < 8; ++mt)
          wB[mt] = *(const bf16x8*)(wbase + (size_t)(mt * 72 + it + 3) * 512);
      }
    }
  }
  size_t sC = (size_t)(s0 + smp) * CHW;
#pragma unroll
  for (int mt = 0; mt < 8; ++mt) {
    int co = half * 128 + mt * 16 + kg * 4;
    float bb[4];
#pragma unroll
    for (int r = 0; r < 4; ++r) bb[r] = hasBR ? bias[co + r] : 0.f;
#pragma unroll
    for (int nt = 0; nt < 2; ++nt) {
      int o = nt * 16 + col;
      if (o >= 25) continue;
#pragma unroll
      for (int r = 0; r < 4; ++r) {
        float v = acc[mt][nt][r] + bb[r];
        if (hasBR) v = fmaxf(v, 0.f);
        if (Y) Y[sC + (size_t)(co + r) * PP + o] = v;
        if (Ybf) Ybf[sC + (size_t)(co + r) * PP + o] = f2b(v);
      }
    }
  }
}

// ---------------------------------------------------------------------------
// pred (transposed bf16 out) = sm[ii]*xs + sum_jj (sm[ij]+1)*relu(cA+cB_j+rb)
// ---------------------------------------------------------------------------
__global__ __launch_bounds__(256) void k_combineT(const float* __restrict__ xs,
    const float* __restrict__ cA, const float* __restrict__ cB,
    const float* __restrict__ sm, const float* __restrict__ rel_b,
    short* __restrict__ predT) {
  __shared__ short lt[25 * CROW];
  int s = blockIdx.x;
  int b = s / 6, i = s % 6;
  const float* smb = sm + (size_t)b * 36;
  float wself = smb[6 * i + i];
  float wr[5]; int js[5];
#pragma unroll
  for (int jj = 0; jj < 5; ++jj) {
    int j = jj + (jj >= i ? 1 : 0);
    js[jj] = j;
    wr[jj] = smb[6 * i + j] + 1.f;
  }
  size_t base = (size_t)s * CHW;
  size_t bbase = (size_t)b * 6 * CHW;
  for (int e = threadIdx.x; e < CHW; e += 256) {
    int ci = e / PP, pq = e - ci * PP;
    float rb = rel_b[ci];
    float av = cA[base + e];
    float acc = wself * xs[base + e];
#pragma unroll
    for (int jj = 0; jj < 5; ++jj) {
      float bvv = cB[bbase + (size_t)js[jj] * CHW + e];
      float rv = av + bvv + rb;
      rv = rv > 0.f ? rv : 0.f;
      acc = fmaf(wr[jj], rv, acc);
    }
    lt[pq * CROW + ci] = f2b(acc);
  }
  __syncthreads();
  short* ob = predT + (size_t)s * CHW;
  for (int c = threadIdx.x; c < 800; c += 256) {
    int pix = c >> 5, ch = c & 31;
    *(int4*)(ob + pix * 256 + ch * 8) = *(const int4*)(lt + pix * CROW + ch * 8);
  }
}

// ---------------------------------------------------------------------------
// LayerNorm over 38400 per batch: v = in1 (+in1b) (+in2); out f32
// ---------------------------------------------------------------------------
__global__ __launch_bounds__(256) void k_ln(const float* __restrict__ in1,
    const float* __restrict__ in1b, const float* __restrict__ in2,
    const float* __restrict__ g, const float* __restrict__ beta,
    float* __restrict__ out) {
  int b = blockIdx.x;
  int t = threadIdx.x;
  const float2* p1 = (const float2*)(in1 + (size_t)b * SAMPLE_F);
  const float2* p1b = in1b ? (const float2*)(in1b + (size_t)b * SAMPLE_F) : nullptr;
  const float2* p2 = in2 ? (const float2*)(in2 + (size_t)b * SAMPLE_F) : nullptr;
  float s = 0.f, s2 = 0.f;
  for (int i = t; i < SAMPLE_F / 2; i += 256) {
    float2 v = p1[i];
    if (p1b) { float2 w = p1b[i]; v.x += w.x; v.y += w.y; }
    if (p2) { float2 w = p2[i]; v.x += w.x; v.y += w.y; }
    s += v.x + v.y;
    s2 += v.x * v.x + v.y * v.y;
  }
#pragma unroll
  for (int off = 32; off >= 1; off >>= 1) {
    s += __shfl_xor(s, off);
    s2 += __shfl_xor(s2, off);
  }
  __shared__ float rs[4], rs2[4];
  int w = t >> 6;
  if ((t & 63) == 0) { rs[w] = s; rs2[w] = s2; }
  __syncthreads();
  float S = rs[0] + rs[1] + rs[2] + rs[3];
  float S2 = rs2[0] + rs2[1] + rs2[2] + rs2[3];
  const float inv_n = 1.f / (float)SAMPLE_F;
  float mean = S * inv_n;
  float var = S2 * inv_n - mean * mean;
  float rstd = 1.f / sqrtf(var + 1e-6f);
  const float2* gp = (const float2*)g;
  const float2* bp = (const float2*)beta;
  float2* op = (float2*)(out + (size_t)b * SAMPLE_F);
  for (int i = t; i < SAMPLE_F / 2; i += 256) {
    float2 v = p1[i];
    if (p1b) { float2 w = p1b[i]; v.x += w.x; v.y += w.y; }
    if (p2) { float2 w2 = p2[i]; v.x += w2.x; v.y += w2.y; }
    float2 gv = gp[i], bvv = bp[i];
    float2 o;
    o.x = (v.x - mean) * rstd * gv.x + bvv.x;
    o.y = (v.y - mean) * rstd * gv.y + bvv.y;
    op[i] = o;
  }
}

// ---------------------------------------------------------------------------
// Final LayerNorm from bf16 streams: v = c0+c1+c2+c3+z (all bf16), f32 out
// ---------------------------------------------------------------------------
__global__ __launch_bounds__(256) void k_lnF2(const short* __restrict__ c0,
    const short* __restrict__ c1, const short* __restrict__ c2,
    const short* __restrict__ c3, const short* __restrict__ z,
    const float* __restrict__ g, const float* __restrict__ beta,
    float* __restrict__ out) {
  int b = blockIdx.x;
  int t = threadIdx.x;
  size_t base = (size_t)b * SAMPLE_F;
  float s = 0.f, s2 = 0.f;
  for (int i = t; i < SAMPLE_F / 8; i += 256) {
    float f0[8], f1[8], f2[8], f3[8], fz[8];
    b8f(*(const int4*)(c0 + base + i * 8), f0);
    b8f(*(const int4*)(c1 + base + i * 8), f1);
    b8f(*(const int4*)(c2 + base + i * 8), f2);
    b8f(*(const int4*)(c3 + base + i * 8), f3);
    b8f(*(const int4*)(z  + base + i * 8), fz);
#pragma unroll
    for (int j = 0; j < 8; ++j) {
      float v = f0[j] + f1[j] + f2[j] + f3[j] + fz[j];
      s += v; s2 += v * v;
    }
  }
#pragma unroll
  for (int off = 32; off >= 1; off >>= 1) {
    s += __shfl_xor(s, off);
    s2 += __shfl_xor(s2, off);
  }
  __shared__ float rs[4], rs2[4];
  int w = t >> 6;
  if ((t & 63) == 0) { rs[w] = s; rs2[w] = s2; }
  __syncthreads();
  float S = rs[0] + rs[1] + rs[2] + rs[3];
  float S2 = rs2[0] + rs2[1] + rs2[2] + rs2[3];
  const float inv_n = 1.f / (float)SAMPLE_F;
  float mean = S * inv_n;
  float var = S2 * inv_n - mean * mean;
  float rstd = 1.f / sqrtf(var + 1e-6f);
  for (int i = t; i < SAMPLE_F / 8; i += 256) {
    float f0[8], f1[8], f2[8], f3[8], fz[8];
    b8f(*(const int4*)(c0 + base + i * 8), f0);
    b8f(*(const int4*)(c1 + base + i * 8), f1);
    b8f(*(const int4*)(c2 + base + i * 8), f2);
    b8f(*(const int4*)(c3 + base + i * 8), f3);
    b8f(*(const int4*)(z  + base + i * 8), fz);
    float4 ga = *(const float4*)(g + i * 8);
    float4 gb = *(const float4*)(g + i * 8 + 4);
    float4 ba = *(const float4*)(beta + i * 8);
    float4 bb = *(const float4*)(beta + i * 8 + 4);
    float gg[8] = {ga.x, ga.y, ga.z, ga.w, gb.x, gb.y, gb.z, gb.w};
    float bt[8] = {ba.x, ba.y, ba.z, ba.w, bb.x, bb.y, bb.z, bb.w};
    float o[8];
#pragma unroll
    for (int j = 0; j < 8; ++j) {
      float v = f0[j] + f1[j] + f2[j] + f3[j] + fz[j];
      o[j] = (v - mean) * rstd * gg[j] + bt[j];
    }
    *(float4*)(out + base + i * 8) = *(float4*)&o[0];
    *(float4*)(out + base + i * 8 + 4) = *(float4*)&o[4];
  }
}

// ---------------------------------------------------------------------------
// LayerNorm with transposed bf16 output: v = in1 + in2; outT[s][pix][ci]
// ---------------------------------------------------------------------------
__global__ __launch_bounds__(256) void k_lnT(const float* __restrict__ in1,
    const float* __restrict__ in2, const float* __restrict__ g,
    const float* __restrict__ beta, short* __restrict__ outT) {
  __shared__ short lt[25 * CROW];
  __shared__ float rs[4], rs2[4];
  int b = blockIdx.x;
  int t = threadIdx.x;
  const float2* p1 = (const float2*)(in1 + (size_t)b * SAMPLE_F);
  const float2* p2 = (const float2*)(in2 + (size_t)b * SAMPLE_F);
  float s = 0.f, s2 = 0.f;
  for (int i = t; i < SAMPLE_F / 2; i += 256) {
    float2 v = p1[i];
    float2 w = p2[i]; v.x += w.x; v.y += w.y;
    s += v.x + v.y;
    s2 += v.x * v.x + v.y * v.y;
  }
#pragma unroll
  for (int off = 32; off >= 1; off >>= 1) {
    s += __shfl_xor(s, off);
    s2 += __shfl_xor(s2, off);
  }
  int w = t >> 6;
  if ((t & 63) == 0) { rs[w] = s; rs2[w] = s2; }
  __syncthreads();
  float S = rs[0] + rs[1] + rs[2] + rs[3];
  float S2 = rs2[0] + rs2[1] + rs2[2] + rs2[3];
  const float inv_n = 1.f / (float)SAMPLE_F;
  float mean = S * inv_n;
  float var = S2 * inv_n - mean * mean;
  float rstd = 1.f / sqrtf(var + 1e-6f);
  const float* i1 = in1 + (size_t)b * SAMPLE_F;
  const float* i2 = in2 + (size_t)b * SAMPLE_F;
  for (int smp = 0; smp < 6; ++smp) {
    int off0 = smp * CHW;
    for (int e = t; e < CHW; e += 256) {
      int idx = off0 + e;
      float v = i1[idx] + i2[idx];
      v = (v - mean) * rstd * g[idx] + beta[idx];
      int ci = e / PP, pq = e - ci * PP;
      lt[pq * CROW + ci] = f2b(v);
    }
    __syncthreads();
    short* ob = outT + (size_t)(b * 6 + smp) * CHW;
    for (int c = t; c < 800; c += 256) {
      int pix = c >> 5, ch = c & 31;
      *(int4*)(ob + pix * 256 + ch * 8) = *(const int4*)(lt + pix * CROW + ch * 8);
    }
    __syncthreads();
  }
}

// ---------------------------------------------------------------------------
// ff GEMM: all-bf16 A and B, split-K4, depth-1 reg prefetch, chunked-XCD
// swizzle, bf16 C partials. Grid 1200 (50n x 6m x 4kz).
// ---------------------------------------------------------------------------
__global__ __launch_bounds__(512) void k_ffgemm7(const short* __restrict__ A,
    const short* __restrict__ Bb, short* __restrict__ C0, short* __restrict__ C1,
    short* __restrict__ C2, short* __restrict__ C3) {
  __shared__ __align__(16) short As[128 * 64];
  __shared__ __align__(16) short Bs[128 * 64];
  int t = threadIdx.x;
  int orig = blockIdx.x;
  int swz = (orig & 7) * 150 + (orig >> 3);
  int m = swz % 6;
  int kz = (swz / 6) & 3;
  int n = swz / 24;
  int m0 = m * 128, n0 = n * 128;
  int lane = t & 63, wv = t >> 6;
  int wm = wv >> 2, wn = wv & 3;
  int col = lane & 15, kg = lane >> 4;
  int ra0 = t >> 3, ca0 = t & 7;
  int ra1 = ra0 + 64;

  int4 pa0, pa1, pb0, pb1;
  auto LOADR = [&](int ks) {
    int k0 = (kz * 25 + ks) * 64;
    pa0 = *(const int4*)(A + (size_t)(m0 + ra0) * CHW + k0 + ca0 * 8);
    pa1 = *(const int4*)(A + (size_t)(m0 + ra1) * CHW + k0 + ca0 * 8);
    pb0 = *(const int4*)(Bb + (size_t)(n0 + ra0) * CHW + k0 + ca0 * 8);
    pb1 = *(const int4*)(Bb + (size_t)(n0 + ra1) * CHW + k0 + ca0 * 8);
  };
  auto STORE = [&]() {
    *(int4*)(As + ra0 * 64 + ((ca0 ^ (ra0 & 7)) * 8)) = pa0;
    *(int4*)(As + ra1 * 64 + ((ca0 ^ (ra1 & 7)) * 8)) = pa1;
    *(int4*)(Bs + ra0 * 64 + ((ca0 ^ (ra0 & 7)) * 8)) = pb0;
    *(int4*)(Bs + ra1 * 64 + ((ca0 ^ (ra1 & 7)) * 8)) = pb1;
  };

  f32x4 acc[4][2] = {};
  LOADR(0);
  for (int ks = 0; ks < 25; ++ks) {
    STORE();
    __syncthreads();
    if (ks < 24) LOADR(ks + 1);
#pragma unroll
    for (int s = 0; s < 2; ++s) {
      bf16x8 af[4], bfr[2];
#pragma unroll
      for (int mt = 0; mt < 4; ++mt) {
        int r = wm * 64 + mt * 16 + col;
        af[mt] = *(const bf16x8*)(As + r * 64 + (((s * 4 + kg) ^ (r & 7)) * 8));
      }
#pragma unroll
      for (int nt = 0; nt < 2; ++nt) {
        int r = wn * 32 + nt * 16 + col;
        bfr[nt] = *(const bf16x8*)(Bs + r * 64 + (((s * 4 + kg) ^ (r & 7)) * 8));
      }
#pragma unroll
      for (int mt = 0; mt < 4; ++mt)
#pragma unroll
        for (int nt = 0; nt < 2; ++nt)
          acc[mt][nt] = __builtin_amdgcn_mfma_f32_16x16x32_bf16(af[mt], bfr[nt], acc[mt][nt], 0, 0, 0);
    }
    __syncthreads();
  }
  short* C = (kz == 0) ? C0 : (kz == 1) ? C1 : (kz == 2) ? C2 : C3;
#pragma unroll
  for (int mt = 0; mt < 4; ++mt) {
    int gr = m0 + wm * 64 + mt * 16 + kg * 4;
#pragma unroll
    for (int nt = 0; nt < 2; ++nt) {
      int gc = n0 + wn * 32 + nt * 16 + col;
#pragma unroll
      for (int r = 0; r < 4; ++r)
        C[(size_t)(gr + r) * CHW + gc] = f2b(acc[mt][nt][r]);
    }
  }
}

// ---------------------------------------------------------------------------
extern "C" void kernel_launch(void* const* d_in, const int* in_sizes, int n_in,
                              void* d_out, int out_size, void* d_ws, size_t ws_size,
                              hipStream_t stream) {
  const float* x        = (const float*)d_in[0];
  const float* valid    = (const float*)d_in[1];
  const float* self_w   = (const float*)d_in[3];
  const float* self_b   = (const float*)d_in[4];
  const float* rel_w    = (const float*)d_in[5];
  const float* rel_b    = (const float*)d_in[6];
  const float* aff_w    = (const float*)d_in[7];
  const float* aff_b    = (const float*)d_in[8];
  const float* attn_w   = (const float*)d_in[9];
  const float* attn_b   = (const float*)d_in[10];
  const float* wq       = (const float*)d_in[11];
  const float* aggt_w   = (const float*)d_in[13];
  const float* aggt_b   = (const float*)d_in[14];
  const float* ff_w     = (const float*)d_in[15];
  const float* ln_aff_g = (const float*)d_in[16];
  const float* ln_aff_b = (const float*)d_in[17];
  const float* ln1_g    = (const float*)d_in[18];
  const float* ln1_b    = (const float*)d_in[19];
  const float* ln2_g    = (const float*)d_in[20];
  const float* ln2_b    = (const float*)d_in[21];

  float* ws = (float*)d_ws;
  const size_t S = (size_t)SAMP * CHW;            // 4,915,200 floats
  float* big0 = ws;
  float* big1 = ws + S;
  float* big2 = ws + 2 * S;
  float* regD = ws + 3 * S;
  float* s2d  = regD;                             // attn phase
  short* WbAll = (short*)regD;                    // then 5 x 589,824 shorts
  float* smb  = regD + 1474560;                   // 4,608 floats
  float* fbase = regD + 1474560 + 4608;           // big scratch region
  short* Tbuf = (short*)fbase;                    // XT: 4,915,200 shorts
  short* spA  = Tbuf + 4915200;                   // 3 x 48x25x512
  short* spB  = spA + 1843200;                    // 3 x 56x25x512
  float* qp   = (float*)(spB + 2150400);          // 5 x 768 x 800 f32
  short* Wffb = Tbuf;                             // bf16 ff_w (after all dead)
  short* zb = (short*)big0;                       // bf16 z (aggt out)
  short* C0 = (short*)big1;                       // 4 bf16 partials
  short* C1 = C0 + S;
  short* C2 = (short*)big2;
  short* C3 = C2 + S;
  float* outp = (float*)d_out;

  const size_t WBSZ = (size_t)Dc * KTOT;          // 589,824

  // ---- attention path: s2d + XT, bf16x3 MFMA q-GEMM, attn softmax ----
  k_s2dx<<<SAMP, 256, 0, stream>>>(x, attn_w, attn_b, s2d, Tbuf);
  k_split3<<<48 * 25, 512, 0, stream>>>(s2d, spA, SAMP, 48);
  k_split3<<<56 * 25, 512, 0, stream>>>(wq, spB, QKD, 56);
  dim3 gq(7, 6, 5);
  k_qgemm<<<gq, 512, 0, stream>>>(spA, spB, qp);
  k_attn5<<<Bq, 256, 0, stream>>>(qp, valid, smb);

  // ---- fragment-contiguous weight repack (s2d region now dead) ----
  dim3 grp(2304, 5);
  k_repack5<<<grp, 256, 0, stream>>>(self_w, rel_w, aff_w, aggt_w, WbAll);

  // ---- merged x-convs ----
  dim3 gc3(SAMP / TS, 3);
  k_convT<<<gc3, 256, 0, stream>>>(Tbuf, WbAll, big0, self_b, nullptr, WBSZ, S);

  // ---- pred (writes transposed bf16 directly over Tbuf) ----
  k_combineT<<<SAMP, 256, 0, stream>>>(big0, big1, big2, smb, rel_b, Tbuf);

  // ---- aff conv + ln_aff + ln1 (transposed out) ----
  dim3 gc1(SAMP / TS, 1);
  k_convT<<<gc1, 256, 0, stream>>>(Tbuf, WbAll + 3 * WBSZ, big0, aff_b, nullptr, 0, 0);
  k_ln<<<Bq, 256, 0, stream>>>(big0, nullptr, nullptr, ln_aff_g, ln_aff_b, big1);
  k_lnT<<<Bq, 256, 0, stream>>>(big1, x, ln1_g, ln1_b, Tbuf);

  // ---- aggt conv (bf16-only out), ff_w cvt, ff GEMM, final ln ----
  k_convT<<<gc1, 256, 0, stream>>>(Tbuf, WbAll + 4 * WBSZ, nullptr, aggt_b, zb, 0, 0);
  k_cvtw<<<20000, 256, 0, stream>>>(ff_w, Wffb);   // overwrites Tbuf region (dead)
  k_ffgemm7<<<1200, 512, 0, stream>>>(zb, Wffb, C0, C1, C2, C3);
  k_lnF2<<<Bq, 256, 0, stream>>>(C0, C1, C2, C3, zb, ln2_g, ln2_b, outp);
}

// Round 18
// 536.453 us; speedup vs baseline: 1.4279x; 1.4279x over previous
//
#include <hip/hip_runtime.h>
#include <hip/hip_bf16.h>
#include <math.h>

#define Bq 128
#define Nn 6
#define Dc 256
#define PP 25
#define SAMP 768
#define CHW 6400
#define SAMPLE_F 38400
#define QKD 800
#define KTOT 2304           // 9 taps * 256 ci
#define CROW 264            // LDS row: 256 ci + 8 pad shorts (528 B)
#define CSAMP (26*CROW)     // 25 pixels + 1 zero row
#define TS 2                // samples per conv block
#define NT 4                // n-tiles = TS * 2 pixel-halves

typedef short bf16x8 __attribute__((ext_vector_type(8)));
typedef float f32x4 __attribute__((ext_vector_type(4)));

__device__ __forceinline__ short f2b(float f) {
  unsigned u = __float_as_uint(f);
  unsigned r = (u + 0x7FFFu + ((u >> 16) & 1u)) >> 16;
  return (short)r;
}
__device__ __forceinline__ float b2f(short s) {
  return __uint_as_float(((unsigned)(unsigned short)s) << 16);
}
__device__ __forceinline__ int pack2(short a, short b) {
  return (int)(((unsigned)(unsigned short)a) | (((unsigned)(unsigned short)b) << 16));
}
// 8 bf16 (int4) -> 8 f32
__device__ __forceinline__ void b8f(const int4 v, float* f) {
  unsigned x0 = (unsigned)v.x, x1 = (unsigned)v.y;
  unsigned x2 = (unsigned)v.z, x3 = (unsigned)v.w;
  f[0] = __uint_as_float(x0 << 16); f[1] = __uint_as_float(x0 & 0xffff0000u);
  f[2] = __uint_as_float(x1 << 16); f[3] = __uint_as_float(x1 & 0xffff0000u);
  f[4] = __uint_as_float(x2 << 16); f[5] = __uint_as_float(x2 & 0xffff0000u);
  f[6] = __uint_as_float(x3 << 16); f[7] = __uint_as_float(x3 & 0xffff0000u);
}

// ---------------------------------------------------------------------------
// weight repack (5 sets) into MFMA-fragment-contiguous layout:
// Wpk[z][ct][tap][kb][lane*8+i]
// ---------------------------------------------------------------------------
__global__ __launch_bounds__(256) void k_repack5(const float* __restrict__ self_w,
    const float* __restrict__ rel_w, const float* __restrict__ aff_w,
    const float* __restrict__ aggt_w, short* __restrict__ WbAll) {
  int z = blockIdx.y;
  int idx = blockIdx.x * 256 + threadIdx.x;   // 0..589823
  const float* W; int stride, cioff;
  if (z == 0)      { W = self_w; stride = 2304; cioff = 0; }
  else if (z == 1) { W = rel_w;  stride = 4608; cioff = 0; }
  else if (z == 2) { W = rel_w;  stride = 4608; cioff = 256; }
  else if (z == 3) { W = aff_w;  stride = 2304; cioff = 0; }
  else             { W = aggt_w; stride = 2304; cioff = 0; }
  int chunk = idx >> 9;            // ct*72 + tap*8 + kb
  int within = idx & 511;
  int l = within >> 3, i = within & 7;
  int ct = chunk / 72, rem = chunk - ct * 72;
  int tap = rem >> 3, kb = rem & 7;
  int co = ct * 16 + (l & 15);
  int ci = kb * 32 + (l >> 4) * 8 + i;
  WbAll[(size_t)z * (Dc * KTOT) + idx] =
      f2b(W[(size_t)co * stride + (size_t)(cioff + ci) * 9 + tap]);
}

// ---------------------------------------------------------------------------
// big f32 -> bf16 convert, 8 elems/thread (n = 40,960,000)
// ---------------------------------------------------------------------------
__global__ __launch_bounds__(256) void k_cvtw(const float* __restrict__ in,
    short* __restrict__ out) {
  size_t i = ((size_t)blockIdx.x * 256 + threadIdx.x) * 8;
  float4 a = *(const float4*)(in + i);
  float4 b = *(const float4*)(in + i + 4);
  int4 o;
  o.x = pack2(f2b(a.x), f2b(a.y));
  o.y = pack2(f2b(a.z), f2b(a.w));
  o.z = pack2(f2b(b.x), f2b(b.y));
  o.w = pack2(f2b(b.z), f2b(b.w));
  *(int4*)(out + i) = o;
}

// ---------------------------------------------------------------------------
// fused: 1x1 conv s2d[row, c*25+pq] + transposed bf16 XT[row][pq][ci]
// ---------------------------------------------------------------------------
__global__ __launch_bounds__(256) void k_s2dx(const float* __restrict__ x,
    const float* __restrict__ attn_w, const float* __restrict__ attn_b,
    float* __restrict__ s2d, short* __restrict__ XT) {
  __shared__ float xs[CHW];
  __shared__ short lt[25 * CROW];
  int row = blockIdx.x;
  int t = threadIdx.x;
  const float* xr = x + (size_t)row * CHW;
  for (int i = t; i < CHW; i += 256) xs[i] = xr[i];
  __syncthreads();
  for (int e = t; e < CHW; e += 256) {
    int ci = e / 25, pq = e - ci * 25;
    lt[pq * CROW + ci] = f2b(xs[e]);
  }
  for (int o = t; o < QKD; o += 256) {
    int c = o / PP, pq = o % PP;
    float acc = attn_b[c];
    const float* wr = attn_w + c * Dc;
    for (int ci = 0; ci < Dc; ++ci) acc += wr[ci] * xs[ci * PP + pq];
    s2d[(size_t)row * QKD + o] = acc;
  }
  __syncthreads();
  short* ob = XT + (size_t)row * CHW;
  for (int c = t; c < 800; c += 256) {
    int pix = c >> 5, ch = c & 31;
    *(int4*)(ob + pix * 256 + ch * 8) = *(const int4*)(lt + pix * CROW + ch * 8);
  }
}

// ---------------------------------------------------------------------------
// 3-way bf16 split + fragment-contiguous repack (both operands, z-gridded)
// z=0: s2d (T=48, R=768) -> spA ; z=1: wq (T=56, R=800) -> spB
// ---------------------------------------------------------------------------
__global__ __launch_bounds__(512) void k_split3b(const float* __restrict__ inA,
    short* __restrict__ plA, const float* __restrict__ inB,
    short* __restrict__ plB) {
  int z = blockIdx.y;
  const float* in = z ? inB : inA;
  short* pl = z ? plB : plA;
  int T = z ? 56 : 48;
  int R = z ? QKD : SAMP;
  int tile = blockIdx.x / 25, kb = blockIdx.x % 25;
  if (tile >= T) return;
  int t = threadIdx.x;
  int l = t >> 3, i = t & 7;
  int row = tile * 16 + (l & 15);
  int k = kb * 32 + (l >> 4) * 8 + i;
  float x = (row < R) ? in[(size_t)row * QKD + k] : 0.f;
  short h = f2b(x);
  float r1 = x - b2f(h);
  short m = f2b(r1);
  float r2 = r1 - b2f(m);
  short lo = f2b(r2);
  size_t PT = (size_t)T * 25 * 512;
  size_t off = ((size_t)tile * 25 + kb) * 512 + t;
  pl[off] = h;
  pl[PT + off] = m;
  pl[2 * PT + off] = lo;
}

// ---------------------------------------------------------------------------
// q GEMM via MFMA, bf16x3 operands (6 products -> ~f32 precision).
// ---------------------------------------------------------------------------
__global__ __launch_bounds__(512) void k_qgemm(const short* __restrict__ Ap,
    const short* __restrict__ Bp, float* __restrict__ qp) {
  int t = threadIdx.x;
  int nT = blockIdx.x, mT = blockIdx.y, kz = blockIdx.z;
  int lane = t & 63, wv = t >> 6;
  int wm = wv >> 2, wn = wv & 3;
  int col = lane & 15, kg = lane >> 4;
  const size_t PTA = (size_t)48 * 25 * 512;
  const size_t PTB = (size_t)56 * 25 * 512;

  f32x4 acc[4][2] = {};
#pragma unroll
  for (int kk = 0; kk < 5; ++kk) {
    int kb = kz * 5 + kk;
    bf16x8 bh[2], bm[2], bl[2];
#pragma unroll
    for (int nt = 0; nt < 2; ++nt) {
      size_t off = ((size_t)(nT * 8 + wn * 2 + nt) * 25 + kb) * 512 + lane * 8;
      bh[nt] = *(const bf16x8*)(Bp + off);
      bm[nt] = *(const bf16x8*)(Bp + PTB + off);
      bl[nt] = *(const bf16x8*)(Bp + 2 * PTB + off);
    }
#pragma unroll
    for (int mt = 0; mt < 4; ++mt) {
      size_t off = ((size_t)(mT * 8 + wm * 4 + mt) * 25 + kb) * 512 + lane * 8;
      bf16x8 ah = *(const bf16x8*)(Ap + off);
      bf16x8 am = *(const bf16x8*)(Ap + PTA + off);
      bf16x8 al = *(const bf16x8*)(Ap + 2 * PTA + off);
#pragma unroll
      for (int nt = 0; nt < 2; ++nt) {
        acc[mt][nt] = __builtin_amdgcn_mfma_f32_16x16x32_bf16(ah, bh[nt], acc[mt][nt], 0, 0, 0);
        acc[mt][nt] = __builtin_amdgcn_mfma_f32_16x16x32_bf16(ah, bm[nt], acc[mt][nt], 0, 0, 0);
        acc[mt][nt] = __builtin_amdgcn_mfma_f32_16x16x32_bf16(am, bh[nt], acc[mt][nt], 0, 0, 0);
        acc[mt][nt] = __builtin_amdgcn_mfma_f32_16x16x32_bf16(ah, bl[nt], acc[mt][nt], 0, 0, 0);
        acc[mt][nt] = __builtin_amdgcn_mfma_f32_16x16x32_bf16(al, bh[nt], acc[mt][nt], 0, 0, 0);
        acc[mt][nt] = __builtin_amdgcn_mfma_f32_16x16x32_bf16(am, bm[nt], acc[mt][nt], 0, 0, 0);
      }
    }
  }
  float* Q = qp + (size_t)kz * SAMP * QKD;
#pragma unroll
  for (int mt = 0; mt < 4; ++mt) {
    int gr = mT * 128 + wm * 64 + mt * 16 + kg * 4;
#pragma unroll
    for (int nt = 0; nt < 2; ++nt) {
      int gc = nT * 128 + wn * 32 + nt * 16 + col;
      if (gc >= QKD) continue;
#pragma unroll
      for (int r = 0; r < 4; ++r)
        Q[(size_t)(gr + r) * QKD + gc] = acc[mt][nt][r];
    }
  }
}

// ---------------------------------------------------------------------------
// attn: sum 5 q-partials (LDS), 36 dots, masked softmax -> sm[b][36]
// ---------------------------------------------------------------------------
__global__ __launch_bounds__(256) void k_attn5(const float* __restrict__ qp,
    const float* __restrict__ valid, float* __restrict__ sm) {
  __shared__ float q[6 * QKD];
  __shared__ float at[36];
  int b = blockIdx.x, t = threadIdx.x;
  size_t base = (size_t)b * 6 * QKD;
  const size_t PS = (size_t)SAMP * QKD;
  for (int i = t; i < 6 * QKD; i += 256) {
    q[i] = qp[base + i] + qp[PS + base + i] + qp[2 * PS + base + i]
         + qp[3 * PS + base + i] + qp[4 * PS + base + i];
  }
  __syncthreads();
  if (t < 36) {
    int n = t / 6, m = t % 6;
    const float4* qn = (const float4*)&q[n * QKD];
    const float4* qm = (const float4*)&q[m * QKD];
    float acc = 0.f;
    for (int d = 0; d < QKD / 4; ++d) {
      float4 a = qn[d], c = qm[d];
      acc += a.x * c.x + a.y * c.y + a.z * c.z + a.w * c.w;
    }
    at[t] = acc * 0.035355339059327376f * valid[b * 6 + m];
  }
  __syncthreads();
  if (t < 6) {
    float v[6]; float mx = -1e30f;
#pragma unroll
    for (int m = 0; m < 6; ++m) {
      float a = at[t * 6 + m];
      v[m] = (a > 0.f) ? a : -1e30f;
      mx = fmaxf(mx, v[m]);
    }
    float e[6]; float se = 0.f;
#pragma unroll
    for (int m = 0; m < 6; ++m) { e[m] = expf(v[m] - mx); se += e[m]; }
    float sc = 6.f / se;
#pragma unroll
    for (int m = 0; m < 6; ++m) sm[(size_t)b * 36 + t * 6 + m] = e[m] * sc;
  }
}

// ---------------------------------------------------------------------------
// MFMA 3x3 conv from pre-transposed bf16 input XT[s][pix][ci].
// Block: 2 samples x 256 co (4 waves x 64 co, mt=4, nt=4). Grid (384, Z).
// Depth-2 register prefetch of the weight stream (named sets wA/wB).
// [proven round-15 config: 96 us @ MfmaUtil 38%; mt=8 variants spill]
// ---------------------------------------------------------------------------
__global__ __launch_bounds__(256) void k_convT(const short* __restrict__ XT,
    const short* __restrict__ WbBase, float* __restrict__ YBase,
    const float* __restrict__ bias, short* __restrict__ Ybf,
    size_t wStride, size_t yStride) {
  __shared__ __align__(16) short xpt[TS * CSAMP];   // 27,456 B
  int t = threadIdx.x;
  int s0 = blockIdx.x * TS;
  int z = blockIdx.y;
  const short* Wb = WbBase + (size_t)z * wStride;
  float* Y = YBase ? (YBase + (size_t)z * yStride) : nullptr;
  int hasBR = (z == 0);

  if (t < TS * 33) {
    int smp = t / 33, i4 = t - smp * 33;
    *(int4*)(xpt + smp * CSAMP + 25 * CROW + i4 * 8) = int4{0, 0, 0, 0};
  }
  for (int c = t; c < TS * 800; c += 256) {
    int smp = c / 800, rem = c - smp * 800;
    int pix = rem >> 5, ch = rem & 31;
    *(int4*)(xpt + smp * CSAMP + pix * CROW + ch * 8) =
        *(const int4*)(XT + ((size_t)(s0 + smp) * 25 + pix) * 256 + ch * 8);
  }
  __syncthreads();

  int lane = t & 63, wv = t >> 6;
  int col = lane & 15, kg = lane >> 4;
  int cobase = wv * 64;
  const short* wtile[4];
#pragma unroll
  for (int mt = 0; mt < 4; ++mt)
    wtile[mt] = Wb + ((size_t)(wv * 4 + mt) * 72) * 512 + lane * 8;
  int o0 = col, o1 = col + 16;
  int orow0 = o0 / 5, ocol0 = o0 - orow0 * 5;
  int orow1 = o1 / 5, ocol1 = o1 - orow1 * 5;

  bf16x8 wA[4], wB[4];
#pragma unroll
  for (int mt = 0; mt < 4; ++mt) wA[mt] = *(const bf16x8*)(wtile[mt]);
#pragma unroll
  for (int mt = 0; mt < 4; ++mt) wB[mt] = *(const bf16x8*)(wtile[mt] + 512);

  f32x4 acc[4][NT] = {};
  for (int tap = 0; tap < 9; ++tap) {
    int dh = tap / 3 - 1, dw = tap % 3 - 1;
    int pb[NT];
#pragma unroll
    for (int nt = 0; nt < NT; ++nt) {
      int hi = nt & 1;
      int irow = (hi ? orow1 : orow0) + dh;
      int icol = (hi ? ocol1 : ocol0) + dw;
      bool good = ((unsigned)irow < 5u) && ((unsigned)icol < 5u) &&
                  (hi ? (o1 < 25) : true);
      int pix = good ? irow * 5 + icol : 25;
      pb[nt] = (nt >> 1) * CSAMP + pix * CROW + kg * 8;
    }
#pragma unroll
    for (int kb2 = 0; kb2 < 4; ++kb2) {
      int it = tap * 8 + kb2 * 2;
      {
        int kb = kb2 * 2;
        bf16x8 bfr[NT];
#pragma unroll
        for (int nt = 0; nt < NT; ++nt)
          bfr[nt] = *(const bf16x8*)(xpt + pb[nt] + kb * 32);
#pragma unroll
        for (int mt = 0; mt < 4; ++mt)
#pragma unroll
          for (int nt = 0; nt < NT; ++nt)
            acc[mt][nt] = __builtin_amdgcn_mfma_f32_16x16x32_bf16(wA[mt], bfr[nt], acc[mt][nt], 0, 0, 0);
      }
      if (it + 2 < 72) {
#pragma unroll
        for (int mt = 0; mt < 4; ++mt)
          wA[mt] = *(const bf16x8*)(wtile[mt] + (size_t)(it + 2) * 512);
      }
      {
        int kb = kb2 * 2 + 1;
        bf16x8 bfr[NT];
#pragma unroll
        for (int nt = 0; nt < NT; ++nt)
          bfr[nt] = *(const bf16x8*)(xpt + pb[nt] + kb * 32);
#pragma unroll
        for (int mt = 0; mt < 4; ++mt)
#pragma unroll
          for (int nt = 0; nt < NT; ++nt)
            acc[mt][nt] = __builtin_amdgcn_mfma_f32_16x16x32_bf16(wB[mt], bfr[nt], acc[mt][nt], 0, 0, 0);
      }
      if (it + 3 < 72) {
#pragma unroll
        for (int mt = 0; mt < 4; ++mt)
          wB[mt] = *(const bf16x8*)(wtile[mt] + (size_t)(it + 3) * 512);
      }
    }
  }
#pragma unroll
  for (int mt = 0; mt < 4; ++mt) {
    int co = cobase + mt * 16 + kg * 4;
    float bb[4];
#pragma unroll
    for (int r = 0; r < 4; ++r) bb[r] = hasBR ? bias[co + r] : 0.f;
#pragma unroll
    for (int nt = 0; nt < NT; ++nt) {
      int o = (nt & 1) * 16 + col;
      if (o >= 25) continue;
      size_t sbase = (size_t)(s0 + (nt >> 1)) * CHW + o;
#pragma unroll
      for (int r = 0; r < 4; ++r) {
        float v = acc[mt][nt][r] + bb[r];
        if (hasBR) v = fmaxf(v, 0.f);
        if (Y) Y[sbase + (size_t)(co + r) * PP] = v;
        if (Ybf) Ybf[sbase + (size_t)(co + r) * PP] = f2b(v);
      }
    }
  }
}

// ---------------------------------------------------------------------------
// pred (transposed bf16 out) = sm[ii]*xs + sum_jj (sm[ij]+1)*relu(cA+cB_j+rb)
// ---------------------------------------------------------------------------
__global__ __launch_bounds__(256) void k_combineT(const float* __restrict__ xs,
    const float* __restrict__ cA, const float* __restrict__ cB,
    const float* __restrict__ sm, const float* __restrict__ rel_b,
    short* __restrict__ predT) {
  __shared__ short lt[25 * CROW];
  int s = blockIdx.x;
  int b = s / 6, i = s % 6;
  const float* smb = sm + (size_t)b * 36;
  float wself = smb[6 * i + i];
  float wr[5]; int js[5];
#pragma unroll
  for (int jj = 0; jj < 5; ++jj) {
    int j = jj + (jj >= i ? 1 : 0);
    js[jj] = j;
    wr[jj] = smb[6 * i + j] + 1.f;
  }
  size_t base = (size_t)s * CHW;
  size_t bbase = (size_t)b * 6 * CHW;
  for (int e = threadIdx.x; e < CHW; e += 256) {
    int ci = e / PP, pq = e - ci * PP;
    float rb = rel_b[ci];
    float av = cA[base + e];
    float acc = wself * xs[base + e];
#pragma unroll
    for (int jj = 0; jj < 5; ++jj) {
      float bvv = cB[bbase + (size_t)js[jj] * CHW + e];
      float rv = av + bvv + rb;
      rv = rv > 0.f ? rv : 0.f;
      acc = fmaf(wr[jj], rv, acc);
    }
    lt[pq * CROW + ci] = f2b(acc);
  }
  __syncthreads();
  short* ob = predT + (size_t)s * CHW;
  for (int c = threadIdx.x; c < 800; c += 256) {
    int pix = c >> 5, ch = c & 31;
    *(int4*)(ob + pix * 256 + ch * 8) = *(const int4*)(lt + pix * CROW + ch * 8);
  }
}

// ---------------------------------------------------------------------------
// LayerNorm over 38400 per batch: v = in1 (+in1b) (+in2); out f32
// ---------------------------------------------------------------------------
__global__ __launch_bounds__(256) void k_ln(const float* __restrict__ in1,
    const float* __restrict__ in1b, const float* __restrict__ in2,
    const float* __restrict__ g, const float* __restrict__ beta,
    float* __restrict__ out) {
  int b = blockIdx.x;
  int t = threadIdx.x;
  const float2* p1 = (const float2*)(in1 + (size_t)b * SAMPLE_F);
  const float2* p1b = in1b ? (const float2*)(in1b + (size_t)b * SAMPLE_F) : nullptr;
  const float2* p2 = in2 ? (const float2*)(in2 + (size_t)b * SAMPLE_F) : nullptr;
  float s = 0.f, s2 = 0.f;
  for (int i = t; i < SAMPLE_F / 2; i += 256) {
    float2 v = p1[i];
    if (p1b) { float2 w = p1b[i]; v.x += w.x; v.y += w.y; }
    if (p2) { float2 w = p2[i]; v.x += w.x; v.y += w.y; }
    s += v.x + v.y;
    s2 += v.x * v.x + v.y * v.y;
  }
#pragma unroll
  for (int off = 32; off >= 1; off >>= 1) {
    s += __shfl_xor(s, off);
    s2 += __shfl_xor(s2, off);
  }
  __shared__ float rs[4], rs2[4];
  int w = t >> 6;
  if ((t & 63) == 0) { rs[w] = s; rs2[w] = s2; }
  __syncthreads();
  float S = rs[0] + rs[1] + rs[2] + rs[3];
  float S2 = rs2[0] + rs2[1] + rs2[2] + rs2[3];
  const float inv_n = 1.f / (float)SAMPLE_F;
  float mean = S * inv_n;
  float var = S2 * inv_n - mean * mean;
  float rstd = 1.f / sqrtf(var + 1e-6f);
  const float2* gp = (const float2*)g;
  const float2* bp = (const float2*)beta;
  float2* op = (float2*)(out + (size_t)b * SAMPLE_F);
  for (int i = t; i < SAMPLE_F / 2; i += 256) {
    float2 v = p1[i];
    if (p1b) { float2 w = p1b[i]; v.x += w.x; v.y += w.y; }
    if (p2) { float2 w2 = p2[i]; v.x += w2.x; v.y += w2.y; }
    float2 gv = gp[i], bvv = bp[i];
    float2 o;
    o.x = (v.x - mean) * rstd * gv.x + bvv.x;
    o.y = (v.y - mean) * rstd * gv.y + bvv.y;
    op[i] = o;
  }
}

// ---------------------------------------------------------------------------
// Final LayerNorm from bf16 streams: v = c0+c1+c2+c3+z (all bf16), f32 out
// ---------------------------------------------------------------------------
__global__ __launch_bounds__(256) void k_lnF2(const short* __restrict__ c0,
    const short* __restrict__ c1, const short* __restrict__ c2,
    const short* __restrict__ c3, const short* __restrict__ z,
    const float* __restrict__ g, const float* __restrict__ beta,
    float* __restrict__ out) {
  int b = blockIdx.x;
  int t = threadIdx.x;
  size_t base = (size_t)b * SAMPLE_F;
  float s = 0.f, s2 = 0.f;
  for (int i = t; i < SAMPLE_F / 8; i += 256) {
    float f0[8], f1[8], f2[8], f3[8], fz[8];
    b8f(*(const int4*)(c0 + base + i * 8), f0);
    b8f(*(const int4*)(c1 + base + i * 8), f1);
    b8f(*(const int4*)(c2 + base + i * 8), f2);
    b8f(*(const int4*)(c3 + base + i * 8), f3);
    b8f(*(const int4*)(z  + base + i * 8), fz);
#pragma unroll
    for (int j = 0; j < 8; ++j) {
      float v = f0[j] + f1[j] + f2[j] + f3[j] + fz[j];
      s += v; s2 += v * v;
    }
  }
#pragma unroll
  for (int off = 32; off >= 1; off >>= 1) {
    s += __shfl_xor(s, off);
    s2 += __shfl_xor(s2, off);
  }
  __shared__ float rs[4], rs2[4];
  int w = t >> 6;
  if ((t & 63) == 0) { rs[w] = s; rs2[w] = s2; }
  __syncthreads();
  float S = rs[0] + rs[1] + rs[2] + rs[3];
  float S2 = rs2[0] + rs2[1] + rs2[2] + rs2[3];
  const float inv_n = 1.f / (float)SAMPLE_F;
  float mean = S * inv_n;
  float var = S2 * inv_n - mean * mean;
  float rstd = 1.f / sqrtf(var + 1e-6f);
  for (int i = t; i < SAMPLE_F / 8; i += 256) {
    float f0[8], f1[8], f2[8], f3[8], fz[8];
    b8f(*(const int4*)(c0 + base + i * 8), f0);
    b8f(*(const int4*)(c1 + base + i * 8), f1);
    b8f(*(const int4*)(c2 + base + i * 8), f2);
    b8f(*(const int4*)(c3 + base + i * 8), f3);
    b8f(*(const int4*)(z  + base + i * 8), fz);
    float4 ga = *(const float4*)(g + i * 8);
    float4 gb = *(const float4*)(g + i * 8 + 4);
    float4 ba = *(const float4*)(beta + i * 8);
    float4 bb = *(const float4*)(beta + i * 8 + 4);
    float gg[8] = {ga.x, ga.y, ga.z, ga.w, gb.x, gb.y, gb.z, gb.w};
    float bt[8] = {ba.x, ba.y, ba.z, ba.w, bb.x, bb.y, bb.z, bb.w};
    float o[8];
#pragma unroll
    for (int j = 0; j < 8; ++j) {
      float v = f0[j] + f1[j] + f2[j] + f3[j] + fz[j];
      o[j] = (v - mean) * rstd * gg[j] + bt[j];
    }
    *(float4*)(out + base + i * 8) = *(float4*)&o[0];
    *(float4*)(out + base + i * 8 + 4) = *(float4*)&o[4];
  }
}

// ---------------------------------------------------------------------------
// LayerNorm with transposed bf16 output: v = in1 + in2; outT[s][pix][ci]
// ---------------------------------------------------------------------------
__global__ __launch_bounds__(256) void k_lnT(const float* __restrict__ in1,
    const float* __restrict__ in2, const float* __restrict__ g,
    const float* __restrict__ beta, short* __restrict__ outT) {
  __shared__ short lt[25 * CROW];
  __shared__ float rs[4], rs2[4];
  int b = blockIdx.x;
  int t = threadIdx.x;
  const float2* p1 = (const float2*)(in1 + (size_t)b * SAMPLE_F);
  const float2* p2 = (const float2*)(in2 + (size_t)b * SAMPLE_F);
  float s = 0.f, s2 = 0.f;
  for (int i = t; i < SAMPLE_F / 2; i += 256) {
    float2 v = p1[i];
    float2 w = p2[i]; v.x += w.x; v.y += w.y;
    s += v.x + v.y;
    s2 += v.x * v.x + v.y * v.y;
  }
#pragma unroll
  for (int off = 32; off >= 1; off >>= 1) {
    s += __shfl_xor(s, off);
    s2 += __shfl_xor(s2, off);
  }
  int w = t >> 6;
  if ((t & 63) == 0) { rs[w] = s; rs2[w] = s2; }
  __syncthreads();
  float S = rs[0] + rs[1] + rs[2] + rs[3];
  float S2 = rs2[0] + rs2[1] + rs2[2] + rs2[3];
  const float inv_n = 1.f / (float)SAMPLE_F;
  float mean = S * inv_n;
  float var = S2 * inv_n - mean * mean;
  float rstd = 1.f / sqrtf(var + 1e-6f);
  const float* i1 = in1 + (size_t)b * SAMPLE_F;
  const float* i2 = in2 + (size_t)b * SAMPLE_F;
  for (int smp = 0; smp < 6; ++smp) {
    int off0 = smp * CHW;
    for (int e = t; e < CHW; e += 256) {
      int idx = off0 + e;
      float v = i1[idx] + i2[idx];
      v = (v - mean) * rstd * g[idx] + beta[idx];
      int ci = e / PP, pq = e - ci * PP;
      lt[pq * CROW + ci] = f2b(v);
    }
    __syncthreads();
    short* ob = outT + (size_t)(b * 6 + smp) * CHW;
    for (int c = t; c < 800; c += 256) {
      int pix = c >> 5, ch = c & 31;
      *(int4*)(ob + pix * 256 + ch * 8) = *(const int4*)(lt + pix * CROW + ch * 8);
    }
    __syncthreads();
  }
}

// ---------------------------------------------------------------------------
// ff GEMM: all-bf16 A and B, split-K4, depth-1 reg prefetch, chunked-XCD
// swizzle, bf16 C partials. Grid 1200 (50n x 6m x 4kz).
// ---------------------------------------------------------------------------
__global__ __launch_bounds__(512) void k_ffgemm7(const short* __restrict__ A,
    const short* __restrict__ Bb, short* __restrict__ C0, short* __restrict__ C1,
    short* __restrict__ C2, short* __restrict__ C3) {
  __shared__ __align__(16) short As[128 * 64];
  __shared__ __align__(16) short Bs[128 * 64];
  int t = threadIdx.x;
  int orig = blockIdx.x;
  int swz = (orig & 7) * 150 + (orig >> 3);
  int m = swz % 6;
  int kz = (swz / 6) & 3;
  int n = swz / 24;
  int m0 = m * 128, n0 = n * 128;
  int lane = t & 63, wv = t >> 6;
  int wm = wv >> 2, wn = wv & 3;
  int col = lane & 15, kg = lane >> 4;
  int ra0 = t >> 3, ca0 = t & 7;
  int ra1 = ra0 + 64;

  int4 pa0, pa1, pb0, pb1;
  auto LOADR = [&](int ks) {
    int k0 = (kz * 25 + ks) * 64;
    pa0 = *(const int4*)(A + (size_t)(m0 + ra0) * CHW + k0 + ca0 * 8);
    pa1 = *(const int4*)(A + (size_t)(m0 + ra1) * CHW + k0 + ca0 * 8);
    pb0 = *(const int4*)(Bb + (size_t)(n0 + ra0) * CHW + k0 + ca0 * 8);
    pb1 = *(const int4*)(Bb + (size_t)(n0 + ra1) * CHW + k0 + ca0 * 8);
  };
  auto STORE = [&]() {
    *(int4*)(As + ra0 * 64 + ((ca0 ^ (ra0 & 7)) * 8)) = pa0;
    *(int4*)(As + ra1 * 64 + ((ca0 ^ (ra1 & 7)) * 8)) = pa1;
    *(int4*)(Bs + ra0 * 64 + ((ca0 ^ (ra0 & 7)) * 8)) = pb0;
    *(int4*)(Bs + ra1 * 64 + ((ca0 ^ (ra1 & 7)) * 8)) = pb1;
  };

  f32x4 acc[4][2] = {};
  LOADR(0);
  for (int ks = 0; ks < 25; ++ks) {
    STORE();
    __syncthreads();
    if (ks < 24) LOADR(ks + 1);
#pragma unroll
    for (int s = 0; s < 2; ++s) {
      bf16x8 af[4], bfr[2];
#pragma unroll
      for (int mt = 0; mt < 4; ++mt) {
        int r = wm * 64 + mt * 16 + col;
        af[mt] = *(const bf16x8*)(As + r * 64 + (((s * 4 + kg) ^ (r & 7)) * 8));
      }
#pragma unroll
      for (int nt = 0; nt < 2; ++nt) {
        int r = wn * 32 + nt * 16 + col;
        bfr[nt] = *(const bf16x8*)(Bs + r * 64 + (((s * 4 + kg) ^ (r & 7)) * 8));
      }
#pragma unroll
      for (int mt = 0; mt < 4; ++mt)
#pragma unroll
        for (int nt = 0; nt < 2; ++nt)
          acc[mt][nt] = __builtin_amdgcn_mfma_f32_16x16x32_bf16(af[mt], bfr[nt], acc[mt][nt], 0, 0, 0);
    }
    __syncthreads();
  }
  short* C = (kz == 0) ? C0 : (kz == 1) ? C1 : (kz == 2) ? C2 : C3;
#pragma unroll
  for (int mt = 0; mt < 4; ++mt) {
    int gr = m0 + wm * 64 + mt * 16 + kg * 4;
#pragma unroll
    for (int nt = 0; nt < 2; ++nt) {
      int gc = n0 + wn * 32 + nt * 16 + col;
#pragma unroll
      for (int r = 0; r < 4; ++r)
        C[(size_t)(gr + r) * CHW + gc] = f2b(acc[mt][nt][r]);
    }
  }
}

// ---------------------------------------------------------------------------
extern "C" void kernel_launch(void* const* d_in, const int* in_sizes, int n_in,
                              void* d_out, int out_size, void* d_ws, size_t ws_size,
                              hipStream_t stream) {
  const float* x        = (const float*)d_in[0];
  const float* valid    = (const float*)d_in[1];
  const float* self_w   = (const float*)d_in[3];
  const float* self_b   = (const float*)d_in[4];
  const float* rel_w    = (const float*)d_in[5];
  const float* rel_b    = (const float*)d_in[6];
  const float* aff_w    = (const float*)d_in[7];
  const float* aff_b    = (const float*)d_in[8];
  const float* attn_w   = (const float*)d_in[9];
  const float* attn_b   = (const float*)d_in[10];
  const float* wq       = (const float*)d_in[11];
  const float* aggt_w   = (const float*)d_in[13];
  const float* aggt_b   = (const float*)d_in[14];
  const float* ff_w     = (const float*)d_in[15];
  const float* ln_aff_g = (const float*)d_in[16];
  const float* ln_aff_b = (const float*)d_in[17];
  const float* ln1_g    = (const float*)d_in[18];
  const float* ln1_b    = (const float*)d_in[19];
  const float* ln2_g    = (const float*)d_in[20];
  const float* ln2_b    = (const float*)d_in[21];

  float* ws = (float*)d_ws;
  const size_t S = (size_t)SAMP * CHW;            // 4,915,200 floats
  float* big0 = ws;
  float* big1 = ws + S;
  float* big2 = ws + 2 * S;
  float* regD = ws + 3 * S;
  float* s2d  = regD;                             // attn phase
  short* WbAll = (short*)regD;                    // then 5 x 589,824 shorts
  float* smb  = regD + 1474560;                   // 4,608 floats
  float* fbase = regD + 1474560 + 4608;           // big scratch region
  short* Tbuf = (short*)fbase;                    // XT: 4,915,200 shorts
  short* spA  = Tbuf + 4915200;                   // 3 x 48x25x512
  short* spB  = spA + 1843200;                    // 3 x 56x25x512
  float* qp   = (float*)(spB + 2150400);          // 5 x 768 x 800 f32
  short* Wffb = Tbuf;                             // bf16 ff_w (after all dead)
  short* zb = (short*)big0;                       // bf16 z (aggt out)
  short* C0 = (short*)big1;                       // 4 bf16 partials
  short* C1 = C0 + S;
  short* C2 = (short*)big2;
  short* C3 = C2 + S;
  float* outp = (float*)d_out;

  const size_t WBSZ = (size_t)Dc * KTOT;          // 589,824

  // ---- attention path: s2d + XT, bf16x3 MFMA q-GEMM, attn softmax ----
  k_s2dx<<<SAMP, 256, 0, stream>>>(x, attn_w, attn_b, s2d, Tbuf);
  dim3 gs(56 * 25, 2);
  k_split3b<<<gs, 512, 0, stream>>>(s2d, spA, wq, spB);
  dim3 gq(7, 6, 5);
  k_qgemm<<<gq, 512, 0, stream>>>(spA, spB, qp);
  k_attn5<<<Bq, 256, 0, stream>>>(qp, valid, smb);

  // ---- fragment-contiguous weight repack (s2d region now dead) ----
  dim3 grp(2304, 5);
  k_repack5<<<grp, 256, 0, stream>>>(self_w, rel_w, aff_w, aggt_w, WbAll);

  // ---- merged x-convs ----
  dim3 gc3(SAMP / TS, 3);
  k_convT<<<gc3, 256, 0, stream>>>(Tbuf, WbAll, big0, self_b, nullptr, WBSZ, S);

  // ---- pred (writes transposed bf16 directly over Tbuf) ----
  k_combineT<<<SAMP, 256, 0, stream>>>(big0, big1, big2, smb, rel_b, Tbuf);

  // ---- aff conv + ln_aff + ln1 (transposed out) ----
  dim3 gc1(SAMP / TS, 1);
  k_convT<<<gc1, 256, 0, stream>>>(Tbuf, WbAll + 3 * WBSZ, big0, aff_b, nullptr, 0, 0);
  k_ln<<<Bq, 256, 0, stream>>>(big0, nullptr, nullptr, ln_aff_g, ln_aff_b, big1);
  k_lnT<<<Bq, 256, 0, stream>>>(big1, x, ln1_g, ln1_b, Tbuf);

  // ---- aggt conv (bf16-only out), ff_w cvt, ff GEMM, final ln ----
  k_convT<<<gc1, 256, 0, stream>>>(Tbuf, WbAll + 4 * WBSZ, nullptr, aggt_b, zb, 0, 0);
  k_cvtw<<<20000, 256, 0, stream>>>(ff_w, Wffb);   // overwrites Tbuf region (dead)
  k_ffgemm7<<<1200, 512, 0, stream>>>(zb, Wffb, C0, C1, C2, C3);
  k_lnF2<<<Bq, 256, 0, stream>>>(C0, C1, C2, C3, zb, ln2_g, ln2_b, outp);
}